// Round 12
// baseline (286.684 us; speedup 1.0000x reference)
//
#include <hip/hip_runtime.h>
#include <hip/hip_bf16.h>

#define B_ 2
#define S_ 2048
#define E_ 1024
#define H_ 16
#define D_ 64

typedef __bf16 bf16x8 __attribute__((ext_vector_type(8)));
typedef __bf16 bf16x4 __attribute__((ext_vector_type(4)));
typedef float f32x4 __attribute__((ext_vector_type(4)));

// ws layout in bf16 elements:
//   x_bf     : [4096, 1024]        offset 0         (4194304)
//   qkvw_bf  : [3072, 1024]        offset 4194304   (3145728)
//   projw_bf : [1024, 1024]        offset 7340032   (1048576)
//   qk_bf    : [2][B,H,S,D]        offset 8388608   (8388608)
//   vt_bf    : [B,H,D,S]           offset 16777216  (4194304)
//   attn_bf  : [4096, 1024]        offset 20971520  (4194304)
// total 25165824 elem = 48 MiB

__device__ __forceinline__ f32x4 mfma16(bf16x8 a, bf16x8 b, f32x4 c) {
    return __builtin_amdgcn_mfma_f32_16x16x32_bf16(a, b, c, 0, 0, 0);
}

// async global->LDS, 16B per lane; LDS dest = wave-uniform base + lane*16
__device__ __forceinline__ void gl_lds16(const __bf16* g, __bf16* l) {
    __builtin_amdgcn_global_load_lds(
        (const __attribute__((address_space(1))) unsigned int*)g,
        (__attribute__((address_space(3))) unsigned int*)l, 16, 0, 0);
}

__global__ __launch_bounds__(256) void convert_kernel(
        const float* __restrict__ x, const float* __restrict__ qkvw,
        const float* __restrict__ projw, __bf16* __restrict__ ws) {
    const long NX = 4194304, NW = 3145728;
    long i = (long)(blockIdx.x * 256 + threadIdx.x) * 4;
    const float* src; __bf16* dst; long off;
    if (i < NX)           { src = x;     dst = ws;           off = i; }
    else if (i < NX + NW) { src = qkvw;  dst = ws + NX;      off = i - NX; }
    else                  { src = projw; dst = ws + NX + NW; off = i - NX - NW; }
    float4 v = *(const float4*)(src + off);
    bf16x4 o = { (__bf16)v.x, (__bf16)v.y, (__bf16)v.z, (__bf16)v.w };
    *(bf16x4*)(dst + off) = o;
}

// m97-style GEMM core: 128x128 tile/block (4 waves, 64x64 each), BK=64.
__device__ __forceinline__ void gemm_core(
        const __bf16* __restrict__ A, const __bf16* __restrict__ Bm,
        int rowT, int colT, int K,
        __bf16* AT, __bf16* BT, f32x4 acc[4][4]) {
    int tid = threadIdx.x;
    int wave = tid >> 6, lane = tid & 63;
    int quad = lane >> 4, lm = lane & 15;
    int wy = wave >> 1, wx = wave & 1;
    int srow = wave * 8 + (lane >> 3);
    int schunk = lane & 7;
    const __bf16* ap = A + (long)(rowT + srow) * K + schunk * 8;
    const __bf16* bp = Bm + (long)(colT + srow) * K + schunk * 8;
    for (int k0 = 0; k0 < K; k0 += 64) {
        __syncthreads();
        for (int i = 0; i < 4; i++) {
            gl_lds16(ap + (long)i * 32 * K + k0, AT + (i * 256 + wave * 64) * 8);
            gl_lds16(bp + (long)i * 32 * K + k0, BT + (i * 256 + wave * 64) * 8);
        }
        __syncthreads();
        for (int ks = 0; ks < 2; ks++) {
            bf16x8 af[4], bfr[4];
            for (int m = 0; m < 4; m++)
                af[m] = *(const bf16x8*)(AT + (wy * 64 + m * 16 + lm) * 64 + ks * 32 + quad * 8);
            for (int n = 0; n < 4; n++)
                bfr[n] = *(const bf16x8*)(BT + (wx * 64 + n * 16 + lm) * 64 + ks * 32 + quad * 8);
            for (int m = 0; m < 4; m++)
                for (int n = 0; n < 4; n++)
                    acc[m][n] = mfma16(af[m], bfr[n], acc[m][n]);
        }
    }
}

// 128x64 variant: 4 waves of 32x64 each -> 2x the blocks (2 blocks/CU).
__device__ __forceinline__ void gemm_core_h(
        const __bf16* __restrict__ A, const __bf16* __restrict__ Bm,
        int rowT, int colT, int K,
        __bf16* AT, __bf16* BT, f32x4 acc[2][4]) {
    int tid = threadIdx.x;
    int wave = tid >> 6, lane = tid & 63;
    int quad = lane >> 4, lm = lane & 15;
    int srow = wave * 8 + (lane >> 3);
    int schunk = lane & 7;
    const __bf16* ap = A + (long)(rowT + srow) * K + schunk * 8;
    const __bf16* bp = Bm + (long)(colT + srow) * K + schunk * 8;
    for (int k0 = 0; k0 < K; k0 += 64) {
        __syncthreads();
        for (int i = 0; i < 4; i++)
            gl_lds16(ap + (long)i * 32 * K + k0, AT + (i * 256 + wave * 64) * 8);
        for (int i = 0; i < 2; i++)
            gl_lds16(bp + (long)i * 32 * K + k0, BT + (i * 256 + wave * 64) * 8);
        __syncthreads();
        for (int ks = 0; ks < 2; ks++) {
            bf16x8 af[2], bfr[4];
            for (int m = 0; m < 2; m++)
                af[m] = *(const bf16x8*)(AT + (wave * 32 + m * 16 + lm) * 64 + ks * 32 + quad * 8);
            for (int n = 0; n < 4; n++)
                bfr[n] = *(const bf16x8*)(BT + (n * 16 + lm) * 64 + ks * 32 + quad * 8);
            for (int m = 0; m < 2; m++)
                for (int n = 0; n < 4; n++)
                    acc[m][n] = mfma16(af[m], bfr[n], acc[m][n]);
        }
    }
}

#define C1 0.18033688011112043f   // 0.125 * log2(e)

// Q,K: C[t, col] = x @ qkv_w[col,:]^T + b. Q pre-scaled by C1 (log2 domain).
__global__ __launch_bounds__(256, 2) void qkv_gemm(
        const __bf16* __restrict__ xbf, const __bf16* __restrict__ wbf,
        const float* __restrict__ bias, __bf16* __restrict__ qk) {
    __shared__ __align__(16) __bf16 AT[128 * 64];
    __shared__ __align__(16) __bf16 BT[128 * 64];
    f32x4 acc[4][4] = {};
    int rowT = blockIdx.x * 128, colT = blockIdx.y * 128;
    gemm_core(xbf, wbf, rowT, colT, E_, AT, BT, acc);
    int wave = threadIdx.x >> 6, lane = threadIdx.x & 63;
    int quad = lane >> 4, lm = lane & 15;
    int wy = wave >> 1, wx = wave & 1;
    for (int n = 0; n < 4; n++) {
        int col = colT + wx * 64 + n * 16 + lm;
        float bv = bias[col];
        int which = col >> 10, rem = col & 1023;
        int h = rem >> 6, d = rem & 63;
        float sc = which ? 1.f : C1;
        for (int m = 0; m < 4; m++) {
            int rowb = rowT + wy * 64 + m * 16 + quad * 4;
            for (int r = 0; r < 4; r++) {
                int row = rowb + r;
                int b = row >> 11, s = row & 2047;
                float v = (acc[m][n][r] + bv) * sc;
                qk[(long)((which * B_ + b) * H_ + h) * (S_ * D_) + (long)s * D_ + d] = (__bf16)v;
            }
        }
    }
}

// VT[(b,h,d), t]: A = Wv rows (M=1024), B = x (N=4096 tokens); 128x64 tiles.
__global__ __launch_bounds__(256, 2) void vt_gemm(
        const __bf16* __restrict__ xbf, const __bf16* __restrict__ wvbf,
        const float* __restrict__ bias, __bf16* __restrict__ vt) {
    __shared__ __align__(16) __bf16 AT[128 * 64];
    __shared__ __align__(16) __bf16 BT[64 * 64];
    f32x4 acc[2][4] = {};
    int rowT = blockIdx.x * 128, colT = blockIdx.y * 64;
    gemm_core_h(wvbf, xbf, rowT, colT, E_, AT, BT, acc);
    int wave = threadIdx.x >> 6, lane = threadIdx.x & 63;
    int quad = lane >> 4, lm = lane & 15;
    for (int n = 0; n < 4; n++) {
        int t = colT + n * 16 + lm;
        int b = t >> 11, s = t & 2047;
        for (int m = 0; m < 2; m++) {
            int rowb = rowT + wave * 32 + m * 16 + quad * 4;
            for (int r = 0; r < 4; r++) {
                int mr = rowb + r;          // v-row: h*64+d
                int h = mr >> 6, d = mr & 63;
                float v = acc[m][n][r] + bias[2048 + mr];
                vt[(long)((b * H_ + h) * D_ + d) * S_ + s] = (__bf16)v;
            }
        }
    }
}

// r12: VALU-pipe diet. Model (fits r8/r10/r11 invariances): flash is VALU-pipe
// THROUGHPUT bound — VALUBusy 30% counts issue slots (1cyc) but wave64 VALU
// occupies the SIMD-32 pipe 2cyc (8cyc for v_exp quarter-rate): ~750 instrs/
// wave-iter -> ~1700 pipe-cyc x2 waves ~= 70% of the 5000-cyc wall. Cuts:
// (1) raw __builtin_amdgcn_exp2f — no libm guard (inputs normal or huge-neg);
// (2) -32 shift folded into MFMA C-init (matrix pipe, free);
// (3) packed v_cvt_pk via __float22bfloat162_rn — 1 instr / 2 scores;
// (4) l via ones-MFMA: Ol[r]=l[q=quad*4+r] in C-layout — deletes 32 adds/iter
//     + all end shuffles, and l sums the exact bf16 P used in PV;
// (5) r11 prefetch reverted (proved neutral — loads aren't the stall).
__global__ __launch_bounds__(256, 2) void flash_attn(
        const __bf16* __restrict__ qk, const __bf16* __restrict__ vt,
        const int* __restrict__ mask, __bf16* __restrict__ attn) {
    int wave = threadIdx.x >> 6, lane = threadIdx.x & 63;
    int quad = lane >> 4, lm = lane & 15;
    int bh = blockIdx.x;      // 0..31  (XCD = bh % 8)
    int qt = blockIdx.y;      // 0..15
    int b = bh >> 4, h = bh & 15;
    const long BHSD = (long)B_ * H_ * S_ * D_;
    const __bf16* qp  = qk + (long)bh * (S_ * D_);
    const __bf16* kp  = qk + BHSD + (long)bh * (S_ * D_);
    const __bf16* vtp = vt + (long)bh * (D_ * S_);   // [d][s]
    const int* mrow = mask + b * S_;

    int q0[2];
    q0[0] = qt * 128 + wave * 16;
    q0[1] = q0[0] + 64;
    bf16x8 qa[2][2];
    for (int t = 0; t < 2; t++)
        for (int x = 0; x < 2; x++)
            qa[t][x] = *(const bf16x8*)(qp + (long)(q0[t] + lm) * D_ + x * 32 + quad * 8);

    f32x4 O[2][4] = {};
    f32x4 Ol[2] = {};                       // l via ones-MFMA (C-layout rows)
    bf16x8 ones8;
    for (int j = 0; j < 8; j++) ones8[j] = (__bf16)1.0f;
    const f32x4 zinit = {-32.f, -32.f, -32.f, -32.f};   // fixed-max shift

    __shared__ __bf16 Plds[4][2][16][72];   // 64 keys + 8 pad per q-row

    struct __align__(8) bfx4 { __hip_bfloat162 lo, hi; };

    for (int kb = 0; kb < S_; kb += 64) {
        bf16x8 kf[4][2];
        int4 mq[4];
        for (int hh = 0; hh < 4; hh++) {
            const __bf16* krow = kp + (long)(kb + hh * 16 + lm) * D_ + quad * 8;
            kf[hh][0] = *(const bf16x8*)(krow);
            kf[hh][1] = *(const bf16x8*)(krow + 32);
            mq[hh] = *(const int4*)(mrow + kb + hh * 16 + quad * 4);
        }
        bf16x8 vf[4][2];
        for (int c = 0; c < 4; c++) {
            const __bf16* vrow = vtp + (long)(c * 16 + lm) * S_ + kb + quad * 8;
            vf[c][0] = *(const bf16x8*)(vrow);
            vf[c][1] = *(const bf16x8*)(vrow + 32);
        }
        // S^T[key][q] already shifted by -32 via C-init (log2 domain)
        f32x4 st[2][4];
        for (int hh = 0; hh < 4; hh++)
            for (int t = 0; t < 2; t++) {
                f32x4 z = mfma16(kf[hh][0], qa[t][0], zinit);
                st[t][hh] = mfma16(kf[hh][1], qa[t][1], z);
            }
        // p = exp2(masked score); raw v_exp (2^-45..2^-22 normal; -1e38 -> 0)
        for (int t = 0; t < 2; t++)
            for (int hh = 0; hh < 4; hh++) {
                float e0 = __builtin_amdgcn_exp2f(mq[hh].x ? st[t][hh][0] : -1e38f);
                float e1 = __builtin_amdgcn_exp2f(mq[hh].y ? st[t][hh][1] : -1e38f);
                float e2 = __builtin_amdgcn_exp2f(mq[hh].z ? st[t][hh][2] : -1e38f);
                float e3 = __builtin_amdgcn_exp2f(mq[hh].w ? st[t][hh][3] : -1e38f);
                bfx4 pk;
                pk.lo = __float22bfloat162_rn(float2{e0, e1});
                pk.hi = __float22bfloat162_rn(float2{e2, e3});
                *(bfx4*)(&Plds[wave][t][lm][hh * 16 + quad * 4]) = pk;
            }
        for (int t = 0; t < 2; t++) {
            bf16x8 pa0 = *(const bf16x8*)(&Plds[wave][t][lm][quad * 8]);
            bf16x8 pa1 = *(const bf16x8*)(&Plds[wave][t][lm][32 + quad * 8]);
            for (int c = 0; c < 4; c++) {
                O[t][c] = mfma16(pa0, vf[c][0], O[t][c]);
                O[t][c] = mfma16(pa1, vf[c][1], O[t][c]);
            }
            Ol[t] = mfma16(pa0, ones8, Ol[t]);
            Ol[t] = mfma16(pa1, ones8, Ol[t]);
        }
    }
    // Ol[r] = l for q = quad*4+r (replicated across lm) — no shuffles needed
    for (int t = 0; t < 2; t++)
        for (int r = 0; r < 4; r++) {
            float lb = Ol[t][r];
            float inv = lb > 0.f ? 1.f / lb : 0.f;
            int s = q0[t] + quad * 4 + r;
            for (int c = 0; c < 4; c++) {
                int e = h * 64 + c * 16 + lm;
                attn[(long)(b * S_ + s) * E_ + e] = (__bf16)(O[t][c][r] * inv);
            }
        }
}

// out[M,N] = A[M,K] @ W[N,K]^T + bias, fp32 out; 128x64 tiles.
__global__ __launch_bounds__(256, 2) void proj_gemm(
        const __bf16* __restrict__ abf, const __bf16* __restrict__ wbf,
        const float* __restrict__ bias, float* __restrict__ out) {
    __shared__ __align__(16) __bf16 AT[128 * 64];
    __shared__ __align__(16) __bf16 BT[64 * 64];
    f32x4 acc[2][4] = {};
    int rowT = blockIdx.x * 128, colT = blockIdx.y * 64;
    gemm_core_h(abf, wbf, rowT, colT, E_, AT, BT, acc);
    int wave = threadIdx.x >> 6, lane = threadIdx.x & 63;
    int quad = lane >> 4, lm = lane & 15;
    for (int n = 0; n < 4; n++) {
        int col = colT + n * 16 + lm;
        float bv = bias[col];
        for (int m = 0; m < 2; m++) {
            int rowb = rowT + wave * 32 + m * 16 + quad * 4;
            for (int r = 0; r < 4; r++) {
                int row = rowb + r;
                out[(long)row * E_ + col] = acc[m][n][r] + bv;
            }
        }
    }
}

extern "C" void kernel_launch(void* const* d_in, const int* in_sizes, int n_in,
                              void* d_out, int out_size, void* d_ws, size_t ws_size,
                              hipStream_t stream) {
    const float* x      = (const float*)d_in[0];
    const int*   mask   = (const int*)d_in[1];
    const float* qkv_w  = (const float*)d_in[2];
    const float* qkv_b  = (const float*)d_in[3];
    const float* proj_w = (const float*)d_in[4];
    const float* proj_b = (const float*)d_in[5];
    float* out = (float*)d_out;
    __bf16* ws = (__bf16*)d_ws;

    __bf16* x_bf     = ws;
    __bf16* qkvw_bf  = ws + 4194304;
    __bf16* projw_bf = ws + 7340032;
    __bf16* qk_bf    = ws + 8388608;
    __bf16* vt_bf    = ws + 16777216;
    __bf16* attn_bf  = ws + 20971520;

    convert_kernel<<<8192, 256, 0, stream>>>(x, qkv_w, proj_w, ws);
    qkv_gemm<<<dim3(32, 16), 256, 0, stream>>>(x_bf, qkvw_bf, qkv_b, qk_bf);
    vt_gemm<<<dim3(8, 64), 256, 0, stream>>>(x_bf, qkvw_bf + 2 * E_ * E_, qkv_b, vt_bf);
    // grid: x = bh (XCD affinity), y = qtile (128 q-rows per block)
    flash_attn<<<dim3(32, 16), 256, 0, stream>>>(qk_bf, vt_bf, mask, attn_bf);
    proj_gemm<<<dim3(32, 16), 256, 0, stream>>>(attn_bf, projw_bf, proj_b, out);
}

// Round 13
// 273.588 us; speedup vs baseline: 1.0479x; 1.0479x over previous
//
#include <hip/hip_runtime.h>
#include <hip/hip_bf16.h>

#define B_ 2
#define S_ 2048
#define E_ 1024
#define H_ 16
#define D_ 64

typedef __bf16 bf16x8 __attribute__((ext_vector_type(8)));
typedef __bf16 bf16x4 __attribute__((ext_vector_type(4)));
typedef float f32x4 __attribute__((ext_vector_type(4)));

// ws layout in bf16 elements:
//   x_bf     : [4096, 1024]        offset 0         (4194304)
//   qkvw_bf  : [3072, 1024]        offset 4194304   (3145728)
//   projw_bf : [1024, 1024]        offset 7340032   (1048576)
//   qk_bf    : [2][B,H,S,D]        offset 8388608   (8388608)
//   vt_bf    : [B,H,D,S]           offset 16777216  (4194304)
//   attn_bf  : [4096, 1024]        offset 20971520  (4194304)
// total 25165824 elem = 48 MiB

__device__ __forceinline__ f32x4 mfma16(bf16x8 a, bf16x8 b, f32x4 c) {
    return __builtin_amdgcn_mfma_f32_16x16x32_bf16(a, b, c, 0, 0, 0);
}

// async global->LDS, 16B per lane; LDS dest = wave-uniform base + lane*16
__device__ __forceinline__ void gl_lds16(const __bf16* g, __bf16* l) {
    __builtin_amdgcn_global_load_lds(
        (const __attribute__((address_space(1))) unsigned int*)g,
        (__attribute__((address_space(3))) unsigned int*)l, 16, 0, 0);
}

__global__ __launch_bounds__(256) void convert_kernel(
        const float* __restrict__ x, const float* __restrict__ qkvw,
        const float* __restrict__ projw, __bf16* __restrict__ ws) {
    const long NX = 4194304, NW = 3145728;
    long i = (long)(blockIdx.x * 256 + threadIdx.x) * 4;
    const float* src; __bf16* dst; long off;
    if (i < NX)           { src = x;     dst = ws;           off = i; }
    else if (i < NX + NW) { src = qkvw;  dst = ws + NX;      off = i - NX; }
    else                  { src = projw; dst = ws + NX + NW; off = i - NX - NW; }
    float4 v = *(const float4*)(src + off);
    bf16x4 o = { (__bf16)v.x, (__bf16)v.y, (__bf16)v.z, (__bf16)v.w };
    *(bf16x4*)(dst + off) = o;
}

// m97-style GEMM core: 128x128 tile/block (4 waves, 64x64 each), BK=64.
__device__ __forceinline__ void gemm_core(
        const __bf16* __restrict__ A, const __bf16* __restrict__ Bm,
        int rowT, int colT, int K,
        __bf16* AT, __bf16* BT, f32x4 acc[4][4]) {
    int tid = threadIdx.x;
    int wave = tid >> 6, lane = tid & 63;
    int quad = lane >> 4, lm = lane & 15;
    int wy = wave >> 1, wx = wave & 1;
    int srow = wave * 8 + (lane >> 3);
    int schunk = lane & 7;
    const __bf16* ap = A + (long)(rowT + srow) * K + schunk * 8;
    const __bf16* bp = Bm + (long)(colT + srow) * K + schunk * 8;
    for (int k0 = 0; k0 < K; k0 += 64) {
        __syncthreads();
        for (int i = 0; i < 4; i++) {
            gl_lds16(ap + (long)i * 32 * K + k0, AT + (i * 256 + wave * 64) * 8);
            gl_lds16(bp + (long)i * 32 * K + k0, BT + (i * 256 + wave * 64) * 8);
        }
        __syncthreads();
        for (int ks = 0; ks < 2; ks++) {
            bf16x8 af[4], bfr[4];
            for (int m = 0; m < 4; m++)
                af[m] = *(const bf16x8*)(AT + (wy * 64 + m * 16 + lm) * 64 + ks * 32 + quad * 8);
            for (int n = 0; n < 4; n++)
                bfr[n] = *(const bf16x8*)(BT + (wx * 64 + n * 16 + lm) * 64 + ks * 32 + quad * 8);
            for (int m = 0; m < 4; m++)
                for (int n = 0; n < 4; n++)
                    acc[m][n] = mfma16(af[m], bfr[n], acc[m][n]);
        }
    }
}

// 128x64 variant: 4 waves of 32x64 each -> 2x the blocks (2 blocks/CU).
__device__ __forceinline__ void gemm_core_h(
        const __bf16* __restrict__ A, const __bf16* __restrict__ Bm,
        int rowT, int colT, int K,
        __bf16* AT, __bf16* BT, f32x4 acc[2][4]) {
    int tid = threadIdx.x;
    int wave = tid >> 6, lane = tid & 63;
    int quad = lane >> 4, lm = lane & 15;
    int srow = wave * 8 + (lane >> 3);
    int schunk = lane & 7;
    const __bf16* ap = A + (long)(rowT + srow) * K + schunk * 8;
    const __bf16* bp = Bm + (long)(colT + srow) * K + schunk * 8;
    for (int k0 = 0; k0 < K; k0 += 64) {
        __syncthreads();
        for (int i = 0; i < 4; i++)
            gl_lds16(ap + (long)i * 32 * K + k0, AT + (i * 256 + wave * 64) * 8);
        for (int i = 0; i < 2; i++)
            gl_lds16(bp + (long)i * 32 * K + k0, BT + (i * 256 + wave * 64) * 8);
        __syncthreads();
        for (int ks = 0; ks < 2; ks++) {
            bf16x8 af[2], bfr[4];
            for (int m = 0; m < 2; m++)
                af[m] = *(const bf16x8*)(AT + (wave * 32 + m * 16 + lm) * 64 + ks * 32 + quad * 8);
            for (int n = 0; n < 4; n++)
                bfr[n] = *(const bf16x8*)(BT + (n * 16 + lm) * 64 + ks * 32 + quad * 8);
            for (int m = 0; m < 2; m++)
                for (int n = 0; n < 4; n++)
                    acc[m][n] = mfma16(af[m], bfr[n], acc[m][n]);
        }
    }
}

#define C1 0.18033688011112043f   // 0.125 * log2(e)

// Q,K: C[t, col] = x @ qkv_w[col,:]^T + b. Q pre-scaled by C1 (log2 domain).
__global__ __launch_bounds__(256, 2) void qkv_gemm(
        const __bf16* __restrict__ xbf, const __bf16* __restrict__ wbf,
        const float* __restrict__ bias, __bf16* __restrict__ qk) {
    __shared__ __align__(16) __bf16 AT[128 * 64];
    __shared__ __align__(16) __bf16 BT[128 * 64];
    f32x4 acc[4][4] = {};
    int rowT = blockIdx.x * 128, colT = blockIdx.y * 128;
    gemm_core(xbf, wbf, rowT, colT, E_, AT, BT, acc);
    int wave = threadIdx.x >> 6, lane = threadIdx.x & 63;
    int quad = lane >> 4, lm = lane & 15;
    int wy = wave >> 1, wx = wave & 1;
    for (int n = 0; n < 4; n++) {
        int col = colT + wx * 64 + n * 16 + lm;
        float bv = bias[col];
        int which = col >> 10, rem = col & 1023;
        int h = rem >> 6, d = rem & 63;
        float sc = which ? 1.f : C1;
        for (int m = 0; m < 4; m++) {
            int rowb = rowT + wy * 64 + m * 16 + quad * 4;
            for (int r = 0; r < 4; r++) {
                int row = rowb + r;
                int b = row >> 11, s = row & 2047;
                float v = (acc[m][n][r] + bv) * sc;
                qk[(long)((which * B_ + b) * H_ + h) * (S_ * D_) + (long)s * D_ + d] = (__bf16)v;
            }
        }
    }
}

// VT[(b,h,d), t]: A = Wv rows (M=1024), B = x (N=4096 tokens); 128x64 tiles.
__global__ __launch_bounds__(256, 2) void vt_gemm(
        const __bf16* __restrict__ xbf, const __bf16* __restrict__ wvbf,
        const float* __restrict__ bias, __bf16* __restrict__ vt) {
    __shared__ __align__(16) __bf16 AT[128 * 64];
    __shared__ __align__(16) __bf16 BT[64 * 64];
    f32x4 acc[2][4] = {};
    int rowT = blockIdx.x * 128, colT = blockIdx.y * 64;
    gemm_core_h(wvbf, xbf, rowT, colT, E_, AT, BT, acc);
    int wave = threadIdx.x >> 6, lane = threadIdx.x & 63;
    int quad = lane >> 4, lm = lane & 15;
    for (int n = 0; n < 4; n++) {
        int t = colT + n * 16 + lm;
        int b = t >> 11, s = t & 2047;
        for (int m = 0; m < 2; m++) {
            int rowb = rowT + wave * 32 + m * 16 + quad * 4;
            for (int r = 0; r < 4; r++) {
                int mr = rowb + r;          // v-row: h*64+d
                int h = mr >> 6, d = mr & 63;
                float v = acc[m][n][r] + bias[2048 + mr];
                vt[(long)((b * H_ + h) * D_ + d) * S_ + s] = (__bf16)v;
            }
        }
    }
}

// r13: 128-key iterations. Empirical law across r1-r12: a wave-iteration
// occupies its SIMD slot ~5.2k cyc nearly independent of content (invariant
// to VMEM count r2, memory level r4, occupancy r10, prefetch r11, VALU count
// r12 — VALUBusy 30.7->13.7% with zero time change). The ONLY historical win
// scaled with iteration count (r5: 64->32 iters = 1.76x). So: amortize the
// fixed per-iteration cost over 2x keys -> 16 iters/wave. Keeps r12's VALU
// diet (raw v_exp, zinit=-32 via MFMA C, packed cvt_pk, l via ones-MFMA).
__global__ __launch_bounds__(256, 2) void flash_attn(
        const __bf16* __restrict__ qk, const __bf16* __restrict__ vt,
        const int* __restrict__ mask, __bf16* __restrict__ attn) {
    int wave = threadIdx.x >> 6, lane = threadIdx.x & 63;
    int quad = lane >> 4, lm = lane & 15;
    int bh = blockIdx.x;      // 0..31  (XCD = bh % 8)
    int qt = blockIdx.y;      // 0..15
    int b = bh >> 4, h = bh & 15;
    const long BHSD = (long)B_ * H_ * S_ * D_;
    const __bf16* qp  = qk + (long)bh * (S_ * D_);
    const __bf16* kp  = qk + BHSD + (long)bh * (S_ * D_);
    const __bf16* vtp = vt + (long)bh * (D_ * S_);   // [d][s]
    const int* mrow = mask + b * S_;

    int q0[2];
    q0[0] = qt * 128 + wave * 16;
    q0[1] = q0[0] + 64;
    bf16x8 qa[2][2];
    for (int t = 0; t < 2; t++)
        for (int x = 0; x < 2; x++)
            qa[t][x] = *(const bf16x8*)(qp + (long)(q0[t] + lm) * D_ + x * 32 + quad * 8);

    f32x4 O[2][4] = {};
    f32x4 Ol[2] = {};                       // l via ones-MFMA (C-layout rows)
    bf16x8 ones8;
    for (int j = 0; j < 8; j++) ones8[j] = (__bf16)1.0f;
    const f32x4 zinit = {-32.f, -32.f, -32.f, -32.f};   // fixed-max shift

    __shared__ __bf16 Plds[4][2][16][136];  // 128 keys + 8 pad per q-row

    struct __align__(8) bfx4 { __hip_bfloat162 lo, hi; };

    for (int kb = 0; kb < S_; kb += 128) {
        // ---- K + mask for 128 keys ----
        bf16x8 kf[8][2];
        int4 mq[8];
        for (int hh = 0; hh < 8; hh++) {
            const __bf16* krow = kp + (long)(kb + hh * 16 + lm) * D_ + quad * 8;
            kf[hh][0] = *(const bf16x8*)(krow);
            kf[hh][1] = *(const bf16x8*)(krow + 32);
            mq[hh] = *(const int4*)(mrow + kb + hh * 16 + quad * 4);
        }
        // ---- QK^T + exp + P-pack, fused per hh (keeps st liveness at 1 hh) ----
        for (int hh = 0; hh < 8; hh++)
            for (int t = 0; t < 2; t++) {
                f32x4 z = mfma16(kf[hh][0], qa[t][0], zinit);
                f32x4 st = mfma16(kf[hh][1], qa[t][1], z);
                float e0 = __builtin_amdgcn_exp2f(mq[hh].x ? st[0] : -1e38f);
                float e1 = __builtin_amdgcn_exp2f(mq[hh].y ? st[1] : -1e38f);
                float e2 = __builtin_amdgcn_exp2f(mq[hh].z ? st[2] : -1e38f);
                float e3 = __builtin_amdgcn_exp2f(mq[hh].w ? st[3] : -1e38f);
                bfx4 pk;
                pk.lo = __float22bfloat162_rn(float2{e0, e1});
                pk.hi = __float22bfloat162_rn(float2{e2, e3});
                *(bfx4*)(&Plds[wave][t][lm][hh * 16 + quad * 4]) = pk;
            }
        // ---- V for 128 keys ----
        bf16x8 vf[4][4];
        for (int c = 0; c < 4; c++) {
            const __bf16* vrow = vtp + (long)(c * 16 + lm) * S_ + kb + quad * 8;
            for (int x = 0; x < 4; x++)
                vf[c][x] = *(const bf16x8*)(vrow + x * 32);
        }
        // ---- PV + l ----
        for (int t = 0; t < 2; t++)
            for (int x = 0; x < 4; x++) {
                bf16x8 pa = *(const bf16x8*)(&Plds[wave][t][lm][x * 32 + quad * 8]);
                for (int c = 0; c < 4; c++)
                    O[t][c] = mfma16(pa, vf[c][x], O[t][c]);
                Ol[t] = mfma16(pa, ones8, Ol[t]);
            }
    }
    // Ol[r] = l for q = quad*4+r (replicated across lm) — no shuffles needed
    for (int t = 0; t < 2; t++)
        for (int r = 0; r < 4; r++) {
            float lb = Ol[t][r];
            float inv = lb > 0.f ? 1.f / lb : 0.f;
            int s = q0[t] + quad * 4 + r;
            for (int c = 0; c < 4; c++) {
                int e = h * 64 + c * 16 + lm;
                attn[(long)(b * S_ + s) * E_ + e] = (__bf16)(O[t][c][r] * inv);
            }
        }
}

// out[M,N] = A[M,K] @ W[N,K]^T + bias, fp32 out; 128x64 tiles.
__global__ __launch_bounds__(256, 2) void proj_gemm(
        const __bf16* __restrict__ abf, const __bf16* __restrict__ wbf,
        const float* __restrict__ bias, float* __restrict__ out) {
    __shared__ __align__(16) __bf16 AT[128 * 64];
    __shared__ __align__(16) __bf16 BT[64 * 64];
    f32x4 acc[2][4] = {};
    int rowT = blockIdx.x * 128, colT = blockIdx.y * 64;
    gemm_core_h(abf, wbf, rowT, colT, E_, AT, BT, acc);
    int wave = threadIdx.x >> 6, lane = threadIdx.x & 63;
    int quad = lane >> 4, lm = lane & 15;
    for (int n = 0; n < 4; n++) {
        int col = colT + n * 16 + lm;
        float bv = bias[col];
        for (int m = 0; m < 2; m++) {
            int rowb = rowT + wave * 32 + m * 16 + quad * 4;
            for (int r = 0; r < 4; r++) {
                int row = rowb + r;
                out[(long)row * E_ + col] = acc[m][n][r] + bv;
            }
        }
    }
}

extern "C" void kernel_launch(void* const* d_in, const int* in_sizes, int n_in,
                              void* d_out, int out_size, void* d_ws, size_t ws_size,
                              hipStream_t stream) {
    const float* x      = (const float*)d_in[0];
    const int*   mask   = (const int*)d_in[1];
    const float* qkv_w  = (const float*)d_in[2];
    const float* qkv_b  = (const float*)d_in[3];
    const float* proj_w = (const float*)d_in[4];
    const float* proj_b = (const float*)d_in[5];
    float* out = (float*)d_out;
    __bf16* ws = (__bf16*)d_ws;

    __bf16* x_bf     = ws;
    __bf16* qkvw_bf  = ws + 4194304;
    __bf16* projw_bf = ws + 7340032;
    __bf16* qk_bf    = ws + 8388608;
    __bf16* vt_bf    = ws + 16777216;
    __bf16* attn_bf  = ws + 20971520;

    convert_kernel<<<8192, 256, 0, stream>>>(x, qkv_w, proj_w, ws);
    qkv_gemm<<<dim3(32, 16), 256, 0, stream>>>(x_bf, qkvw_bf, qkv_b, qk_bf);
    vt_gemm<<<dim3(8, 64), 256, 0, stream>>>(x_bf, qkvw_bf + 2 * E_ * E_, qkv_b, vt_bf);
    // grid: x = bh (XCD affinity), y = qtile (128 q-rows per block)
    flash_attn<<<dim3(32, 16), 256, 0, stream>>>(qk_bf, vt_bf, mask, attn_bf);
    proj_gemm<<<dim3(32, 16), 256, 0, stream>>>(attn_bf, projw_bf, proj_b, out);
}